// Round 1
// baseline (481.369 us; speedup 1.0000x reference)
//
#include <hip/hip_runtime.h>
#include <hip/hip_bf16.h>
#include <stdint.h>

typedef __attribute__((ext_vector_type(8))) __bf16 bf16x8;
typedef __attribute__((ext_vector_type(4))) float f32x4;

#define M_DIM 8192
#define N_DIM 4096
#define K_DIM 4096
// element counts (powers of two -> mean = sum * 2^-n is exact)
#define NX_INV (1.0f / 33554432.0f)
#define NW_INV (1.0f / 16777216.0f)

// CK-style addrspace casts (LDS generic ptr low 32 bits == LDS offset; apertures are 4GB-aligned)
#define AS3(p) ((__attribute__((address_space(3))) uint32_t*)(uint32_t)(uintptr_t)(p))
#define AS1(p) ((const __attribute__((address_space(1))) uint32_t*)(uintptr_t)(p))

// ---------------- sum(|x|) reduction, fp64 atomic accumulation ----------------
__global__ void absum_kernel(const float* __restrict__ x, int n4, double* __restrict__ out) {
    int i = blockIdx.x * blockDim.x + threadIdx.x;
    int stride = gridDim.x * blockDim.x;
    const float4* x4 = (const float4*)x;
    float s = 0.f;
    for (; i < n4; i += stride) {
        float4 v = x4[i];
        s += fabsf(v.x) + fabsf(v.y) + fabsf(v.z) + fabsf(v.w);
    }
    #pragma unroll
    for (int off = 32; off >= 1; off >>= 1) s += __shfl_down(s, off, 64);
    __shared__ float wsum[4];
    int lane = threadIdx.x & 63, wid = threadIdx.x >> 6;
    if (lane == 0) wsum[wid] = s;
    __syncthreads();
    if (threadIdx.x == 0) {
        double tot = (double)wsum[0] + (double)wsum[1] + (double)wsum[2] + (double)wsum[3];
        atomicAdd(out, tot);
    }
}

// ---------------- fp4 e2m1 quant -> bf16 LEVEL CODES (exact) ----------------
// searchsorted(mids, |y|, 'right'): |y| < .25 -> 0; [.25,.75) -> .5; ... ; >= 5 -> 6
__device__ __forceinline__ float fp4_level(float a) {
    float lv;
    if (a < 1.75f) {
        if (a < 0.75f) lv = (a < 0.25f) ? 0.0f : 0.5f;
        else           lv = (a < 1.25f) ? 1.0f : 1.5f;
    } else {
        if (a < 3.5f)  lv = (a < 2.5f) ? 2.0f : 3.0f;
        else           lv = (a < 5.0f) ? 4.0f : 6.0f;
    }
    return lv;
}

__device__ __forceinline__ ushort enc_code(float x, float s) {
    float y = x / s;                       // matches reference's division
    float q = copysignf(fp4_level(fabsf(y)), y);
    __hip_bfloat16 b = __float2bfloat16(q);  // exact: codes need 2 mantissa bits
    return *(ushort*)&b;
}

__global__ void quant_kernel(const float* __restrict__ x, ushort* __restrict__ q,
                             int n4, const double* __restrict__ sum, float invN) {
    float s = (float)(*sum) * invN;        // mean(|x|); *2^-n exact
    int i = blockIdx.x * blockDim.x + threadIdx.x;
    int stride = gridDim.x * blockDim.x;
    const float4* x4 = (const float4*)x;
    for (; i < n4; i += stride) {
        float4 v = x4[i];
        ushort4 o;
        o.x = enc_code(v.x, s);
        o.y = enc_code(v.y, s);
        o.z = enc_code(v.z, s);
        o.w = enc_code(v.w, s);
        *(ushort4*)&q[(size_t)i * 4] = o;
    }
}

// ---------------- bf16 code GEMM: C = (A·B^T)*scale + bias ----------------
// A: [M][K] bf16 codes, B: [N][K] bf16 codes (both K-contiguous)
// 128x128 tile, BK=32, 4 waves (2x2), 16x16x32 MFMA, global_load_lds width-16
#define BM 128
#define BN 128
#define BK 32
#define NWG 2048  // (8192/128)*(4096/128)

__global__ void gemm_kernel(const ushort* __restrict__ A, const ushort* __restrict__ B,
                            const float* __restrict__ bias, float* __restrict__ C,
                            const double* __restrict__ sums) {
    __shared__ ushort As[BM * BK];   // 8 KB
    __shared__ ushort Bs[BN * BK];   // 8 KB

    // XCD-aware swizzle (2048 % 8 == 0 -> bijective)
    int bid = blockIdx.x;
    int swz = (bid & 7) * (NWG >> 3) + (bid >> 3);
    int bn = (swz & 31) * BN;        // 4096/128 = 32 n-tiles
    int bm = (swz >> 5) * BM;

    int t = threadIdx.x;
    int lane = t & 63;
    int wid = t >> 6;
    int wm = (wid >> 1) * 64;        // wave sub-tile origin
    int wn = (wid & 1) * 64;
    int r  = lane & 15;              // fragment row/col
    int kq = lane >> 4;              // k-quarter

    f32x4 acc[4][4];
    #pragma unroll
    for (int i = 0; i < 4; i++)
        #pragma unroll
        for (int j = 0; j < 4; j++) acc[i][j] = (f32x4)0.f;

    // staging source addressing: thread t loads 16B = 8 codes; row=t/4, col8=(t%4)*8
    int arow = t >> 2;
    int acol = (t & 3) * 8;
    const ushort* ga0 = A + (size_t)(bm + arow) * K_DIM + acol;
    const ushort* ga1 = ga0 + (size_t)64 * K_DIM;
    const ushort* gb0 = B + (size_t)(bn + arow) * K_DIM + acol;
    const ushort* gb1 = gb0 + (size_t)64 * K_DIM;

    for (int k0 = 0; k0 < K_DIM; k0 += BK) {
        __syncthreads();   // previous iteration's LDS reads complete
        __builtin_amdgcn_global_load_lds(AS1(ga0 + k0), AS3(&As[t * 8]),        16, 0, 0);
        __builtin_amdgcn_global_load_lds(AS1(ga1 + k0), AS3(&As[2048 + t * 8]), 16, 0, 0);
        __builtin_amdgcn_global_load_lds(AS1(gb0 + k0), AS3(&Bs[t * 8]),        16, 0, 0);
        __builtin_amdgcn_global_load_lds(AS1(gb1 + k0), AS3(&Bs[2048 + t * 8]), 16, 0, 0);
        __syncthreads();   // drains vmcnt(0): staged data visible

        bf16x8 af[4], bfr[4];
        #pragma unroll
        for (int mi = 0; mi < 4; mi++)
            af[mi] = *(const bf16x8*)&As[(wm + mi * 16 + r) * BK + kq * 8];
        #pragma unroll
        for (int ni = 0; ni < 4; ni++)
            bfr[ni] = *(const bf16x8*)&Bs[(wn + ni * 16 + r) * BK + kq * 8];

        #pragma unroll
        for (int mi = 0; mi < 4; mi++)
            #pragma unroll
            for (int ni = 0; ni < 4; ni++)
                acc[mi][ni] = __builtin_amdgcn_mfma_f32_16x16x32_bf16(
                    af[mi], bfr[ni], acc[mi][ni], 0, 0, 0);
    }

    float scale = (float)((sums[0] * (1.0 / 33554432.0)) * (sums[1] * (1.0 / 16777216.0)));

    #pragma unroll
    for (int mi = 0; mi < 4; mi++) {
        int row = bm + wm + mi * 16 + kq * 4;   // C/D: row = (lane>>4)*4 + j
        #pragma unroll
        for (int ni = 0; ni < 4; ni++) {
            int col = bn + wn + ni * 16 + r;    // C/D: col = lane&15
            float bv = bias[col];
            #pragma unroll
            for (int j = 0; j < 4; j++)
                C[(size_t)(row + j) * N_DIM + col] = acc[mi][ni][j] * scale + bv;
        }
    }
}

extern "C" void kernel_launch(void* const* d_in, const int* in_sizes, int n_in,
                              void* d_out, int out_size, void* d_ws, size_t ws_size,
                              hipStream_t stream) {
    const float* x    = (const float*)d_in[0];   // [4,2048,4096]
    const float* w    = (const float*)d_in[1];   // [4096,4096]
    const float* bias = (const float*)d_in[2];   // [4096]
    float* out = (float*)d_out;                  // [4,2048,4096] fp32

    double* sums = (double*)d_ws;                          // sums[0]=sum|x|, sums[1]=sum|w|
    ushort* Xq = (ushort*)((char*)d_ws + 1024);            // 8192*4096 bf16 codes (64 MB)
    ushort* Wq = Xq + (size_t)M_DIM * K_DIM;               // 4096*4096 bf16 codes (32 MB)

    hipMemsetAsync(d_ws, 0, 1024, stream);
    absum_kernel<<<2048, 256, 0, stream>>>(x, 33554432 / 4, sums + 0);
    absum_kernel<<<2048, 256, 0, stream>>>(w, 16777216 / 4, sums + 1);
    quant_kernel<<<2048, 256, 0, stream>>>(x, Xq, 33554432 / 4, sums + 0, NX_INV);
    quant_kernel<<<2048, 256, 0, stream>>>(w, Wq, 16777216 / 4, sums + 1, NW_INV);
    gemm_kernel<<<NWG, 256, 0, stream>>>(Xq, Wq, bias, out, sums);
}

// Round 2
// 376.620 us; speedup vs baseline: 1.2781x; 1.2781x over previous
//
#include <hip/hip_runtime.h>
#include <hip/hip_bf16.h>
#include <stdint.h>

typedef __attribute__((ext_vector_type(8))) __bf16 bf16x8;
typedef __attribute__((ext_vector_type(4))) float f32x4;

#define M_DIM 8192
#define N_DIM 4096
#define K_DIM 4096
#define NX_INV (1.0f / 33554432.0f)
#define NW_INV (1.0f / 16777216.0f)

#define AS3(p) ((__attribute__((address_space(3))) uint32_t*)(uint32_t)(uintptr_t)(p))
#define AS1(p) ((const __attribute__((address_space(1))) uint32_t*)(uintptr_t)(p))

// ---------------- sum(|x|) reduction, fp64 atomic accumulation ----------------
__global__ void absum_kernel(const float* __restrict__ x, int n4, double* __restrict__ out) {
    int i = blockIdx.x * blockDim.x + threadIdx.x;
    int stride = gridDim.x * blockDim.x;
    const float4* x4 = (const float4*)x;
    float s = 0.f;
    for (; i < n4; i += stride) {
        float4 v = x4[i];
        s += fabsf(v.x) + fabsf(v.y) + fabsf(v.z) + fabsf(v.w);
    }
    #pragma unroll
    for (int off = 32; off >= 1; off >>= 1) s += __shfl_down(s, off, 64);
    __shared__ float wsum[4];
    int lane = threadIdx.x & 63, wid = threadIdx.x >> 6;
    if (lane == 0) wsum[wid] = s;
    __syncthreads();
    if (threadIdx.x == 0) {
        double tot = (double)wsum[0] + (double)wsum[1] + (double)wsum[2] + (double)wsum[3];
        atomicAdd(out, tot);
    }
}

// ---------------- fp4 e2m1 quant -> bf16 LEVEL CODES (exact) ----------------
__device__ __forceinline__ float fp4_level(float a) {
    float lv;
    if (a < 1.75f) {
        if (a < 0.75f) lv = (a < 0.25f) ? 0.0f : 0.5f;
        else           lv = (a < 1.25f) ? 1.0f : 1.5f;
    } else {
        if (a < 3.5f)  lv = (a < 2.5f) ? 2.0f : 3.0f;
        else           lv = (a < 5.0f) ? 4.0f : 6.0f;
    }
    return lv;
}

__device__ __forceinline__ ushort enc_code(float x, float s) {
    float y = x / s;
    float q = copysignf(fp4_level(fabsf(y)), y);
    __hip_bfloat16 b = __float2bfloat16(q);
    return *(ushort*)&b;
}

__global__ void quant_kernel(const float* __restrict__ x, ushort* __restrict__ q,
                             int n4, const double* __restrict__ sum, float invN) {
    float s = (float)(*sum) * invN;
    int i = blockIdx.x * blockDim.x + threadIdx.x;
    int stride = gridDim.x * blockDim.x;
    const float4* x4 = (const float4*)x;
    for (; i < n4; i += stride) {
        float4 v = x4[i];
        ushort4 o;
        o.x = enc_code(v.x, s);
        o.y = enc_code(v.y, s);
        o.z = enc_code(v.z, s);
        o.w = enc_code(v.w, s);
        *(ushort4*)&q[(size_t)i * 4] = o;
    }
}

// ---------------- bf16 code GEMM: C = (A·B^T)*scale + bias ----------------
// 256x256 tile, BK=32, 8 waves (2Mx4N), 4-deep LDS ring, counted vmcnt,
// T2 XOR-swizzle (slot ^= (row>>1)&3), T5 setprio around MFMA clusters.
#define BM 256
#define BN 256
#define BK 32
#define NKT 128          // K_DIM / BK
#define NWG 512          // (8192/256)*(4096/256)

__device__ __forceinline__ void glds16(const ushort* g, ushort* l) {
    __builtin_amdgcn_global_load_lds(AS1(g), AS3(l), 16, 0, 0);
}

__global__ __launch_bounds__(512, 2)
void gemm_kernel(const ushort* __restrict__ A, const ushort* __restrict__ B,
                 const float* __restrict__ bias, float* __restrict__ C,
                 const double* __restrict__ sums) {
    // 4 buffers x (A: 256x32 + B: 256x32) bf16 = 128 KB
    __shared__ ushort lds[4 * 16384];

    int bid = blockIdx.x;
    int swz = (bid & 7) * (NWG >> 3) + (bid >> 3);  // 512 % 8 == 0 -> bijective
    int bn = (swz & 15) * BN;        // 16 n-tiles
    int bm = (swz >> 4) * BM;        // 32 m-tiles

    int t = threadIdx.x;
    int lane = t & 63;
    int wid = t >> 6;
    int wm = wid >> 2;               // 0..1 -> rows wm*128
    int wn = wid & 3;                // 0..3 -> cols wn*64
    int r  = lane & 15;
    int kq = lane >> 4;

    // ---- staging addressing (write side linear; swizzle folded into global col) ----
    // thread t fills LDS bytes [t*16, t*16+16) of each 8KB chunk:
    //   row = chunk*128 + t/4, stored slot = t&3
    //   logical slot = (t&3) ^ ((row>>1)&3) = (t&3) ^ ((t>>3)&3)
    int srow = t >> 2;                               // 0..127
    int scol = ((t & 3) ^ ((t >> 3) & 3)) * 8;       // pre-swizzled k-column (ushorts)
    const ushort* gA0 = A + (size_t)(bm + srow) * K_DIM + scol;
    const ushort* gA1 = gA0 + (size_t)128 * K_DIM;
    const ushort* gB0 = B + (size_t)(bn + srow) * K_DIM + scol;
    const ushort* gB1 = gB0 + (size_t)128 * K_DIM;
    int dA0 = t * 8, dA1 = 4096 + t * 8, dB0 = 8192 + t * 8, dB1 = 12288 + t * 8;

    // ---- read-side offsets (swizzled): off = row*32 + ((kq ^ ((row>>1)&3))*8) ----
    int xorterm = (kq ^ ((r >> 1) & 3)) * 8;         // (row>>1)&3 == (r>>1)&3 here
    int offA[8], offB[4];
    #pragma unroll
    for (int m = 0; m < 8; m++) offA[m] = (wm * 128 + m * 16 + r) * 32 + xorterm;
    #pragma unroll
    for (int n = 0; n < 4; n++) offB[n] = 8192 + (wn * 64 + n * 16 + r) * 32 + xorterm;

    f32x4 acc[8][4];
    #pragma unroll
    for (int m = 0; m < 8; m++)
        #pragma unroll
        for (int n = 0; n < 4; n++) acc[m][n] = (f32x4)0.f;

    // ---- prologue: stage K-tiles 0,1,2 (4 loads each, tile order) ----
    #pragma unroll
    for (int pt = 0; pt < 3; pt++) {
        ushort* lb = lds + pt * 16384;
        int ko = pt * BK;
        glds16(gA0 + ko, lb + dA0);
        glds16(gA1 + ko, lb + dA1);
        glds16(gB0 + ko, lb + dB0);
        glds16(gB1 + ko, lb + dB1);
    }

    for (int kt = 0; kt < NKT; kt++) {
        // tile kt must have landed; tiles kt+1, kt+2 (8 loads) may stay in flight
        if (kt < NKT - 2)       asm volatile("s_waitcnt vmcnt(8)" ::: "memory");
        else if (kt == NKT - 2) asm volatile("s_waitcnt vmcnt(4)" ::: "memory");
        else                    asm volatile("s_waitcnt vmcnt(0)" ::: "memory");
        asm volatile("s_barrier" ::: "memory");   // also seals prev iter's reads (WAR)

        const ushort* rb = lds + (kt & 3) * 16384;
        bool st = (kt + 3 < NKT);
        ushort* sb = lds + ((kt + 3) & 3) * 16384;
        int ko = (kt + 3) * BK;

        // ---- phase 0: stage A(kt+3) | read A m0-3, B n0-3 | 16 MFMA ----
        if (st) { glds16(gA0 + ko, sb + dA0); glds16(gA1 + ko, sb + dA1); }
        bf16x8 aF[4], bF[4];
        #pragma unroll
        for (int m = 0; m < 4; m++) aF[m] = *(const bf16x8*)&rb[offA[m]];
        #pragma unroll
        for (int n = 0; n < 4; n++) bF[n] = *(const bf16x8*)&rb[offB[n]];
        __builtin_amdgcn_s_setprio(1);
        #pragma unroll
        for (int m = 0; m < 4; m++)
            #pragma unroll
            for (int n = 0; n < 4; n++)
                acc[m][n] = __builtin_amdgcn_mfma_f32_16x16x32_bf16(aF[m], bF[n], acc[m][n], 0, 0, 0);
        __builtin_amdgcn_s_setprio(0);

        // ---- phase 1: stage B(kt+3) | read A m4-7 (B reused) | 16 MFMA ----
        if (st) { glds16(gB0 + ko, sb + dB0); glds16(gB1 + ko, sb + dB1); }
        bf16x8 aG[4];
        #pragma unroll
        for (int m = 0; m < 4; m++) aG[m] = *(const bf16x8*)&rb[offA[m + 4]];
        __builtin_amdgcn_s_setprio(1);
        #pragma unroll
        for (int m = 0; m < 4; m++)
            #pragma unroll
            for (int n = 0; n < 4; n++)
                acc[m + 4][n] = __builtin_amdgcn_mfma_f32_16x16x32_bf16(aG[m], bF[n], acc[m + 4][n], 0, 0, 0);
        __builtin_amdgcn_s_setprio(0);
    }

    float scale = (float)((sums[0] * (1.0 / 33554432.0)) * (sums[1] * (1.0 / 16777216.0)));

    #pragma unroll
    for (int m = 0; m < 8; m++) {
        int row = bm + wm * 128 + m * 16 + kq * 4;     // C/D: row = (lane>>4)*4 + j
        #pragma unroll
        for (int n = 0; n < 4; n++) {
            int col = bn + wn * 64 + n * 16 + r;       // C/D: col = lane&15
            float bv = bias[col];
            #pragma unroll
            for (int j = 0; j < 4; j++)
                C[(size_t)(row + j) * N_DIM + col] = acc[m][n][j] * scale + bv;
        }
    }
}

extern "C" void kernel_launch(void* const* d_in, const int* in_sizes, int n_in,
                              void* d_out, int out_size, void* d_ws, size_t ws_size,
                              hipStream_t stream) {
    const float* x    = (const float*)d_in[0];   // [4,2048,4096]
    const float* w    = (const float*)d_in[1];   // [4096,4096]
    const float* bias = (const float*)d_in[2];   // [4096]
    float* out = (float*)d_out;                  // [4,2048,4096] fp32

    double* sums = (double*)d_ws;
    ushort* Xq = (ushort*)((char*)d_ws + 1024);            // 64 MB bf16 codes
    ushort* Wq = Xq + (size_t)M_DIM * K_DIM;               // 32 MB bf16 codes

    hipMemsetAsync(d_ws, 0, 1024, stream);
    absum_kernel<<<2048, 256, 0, stream>>>(x, 33554432 / 4, sums + 0);
    absum_kernel<<<2048, 256, 0, stream>>>(w, 16777216 / 4, sums + 1);
    quant_kernel<<<2048, 256, 0, stream>>>(x, Xq, 33554432 / 4, sums + 0, NX_INV);
    quant_kernel<<<2048, 256, 0, stream>>>(w, Wq, 16777216 / 4, sums + 1, NW_INV);
    gemm_kernel<<<NWG, 512, 0, stream>>>(Xq, Wq, bias, out, sums);
}